// Round 11
// baseline (543.996 us; speedup 1.0000x reference)
//
#include <hip/hip_runtime.h>
#include <cstdint>

#define C_DIM 1024
#define T_DIM 2048
#define B_DIM 4
#define FFN_DIM 4096
#define NROWS (B_DIM * T_DIM)                 // 8192 rows (B*T)
#define NELEM ((size_t)NROWS * C_DIM)
#define MB ((size_t)1 << 20)
#define NSEG 32
#define SEGL (T_DIM / NSEG)                   // 64

typedef __bf16 bf16;
typedef __bf16 bf16x4 __attribute__((ext_vector_type(4)));
typedef __bf16 bf16x8 __attribute__((ext_vector_type(8)));
typedef float  floatx4 __attribute__((ext_vector_type(4)));

// async global->LDS, 16B per lane; LDS dest is wave-uniform base + lane*16
#define GLDS(g, l) __builtin_amdgcn_global_load_lds(                          \
    (const __attribute__((address_space(1))) void*)(g),                       \
    (__attribute__((address_space(3))) void*)(l), 16, 0, 0)

// ---------------------------------------------------------------------------
// Weight conversion table (7 fp32->bf16 jobs), folded into pre_kernel.
// ---------------------------------------------------------------------------
struct W7 {
    const float* s[7];
    bf16*        d[7];
    int          cum[8];   // cumulative float4 counts, cum[7] = total
};

// ---------------------------------------------------------------------------
// LayerNorm + token-shift mix body (shared by pre_kernel and lnmix_kernel).
// hx = LN(x[t-1]) (zero row at t==0, matching reference pad-before-shift).
// ---------------------------------------------------------------------------
template<bool HASV>
__device__ __forceinline__ void lnmix_body(int row, int tid,
                                           const float* __restrict__ x,
                                           const float* __restrict__ g,
                                           const float* __restrict__ b,
                                           const float* __restrict__ mk,
                                           const float* __restrict__ mv,
                                           const float* __restrict__ mr,
                                           bf16* __restrict__ xk,
                                           bf16* __restrict__ xv,
                                           bf16* __restrict__ xr)
{
    int t = row & (T_DIM - 1);
    size_t i4 = (size_t)row * 256 + tid;

    float4 v  = ((const float4*)x)[i4];
    float4 vp = make_float4(0.f, 0.f, 0.f, 0.f);
    if (t != 0) vp = ((const float4*)x)[i4 - 256];

    float s   = v.x + v.y + v.z + v.w;
    float s2  = v.x * v.x + v.y * v.y + v.z * v.z + v.w * v.w;
    float sp  = vp.x + vp.y + vp.z + vp.w;
    float sp2 = vp.x * vp.x + vp.y * vp.y + vp.z * vp.z + vp.w * vp.w;
    for (int off = 32; off > 0; off >>= 1) {
        s   += __shfl_down(s,   off);
        s2  += __shfl_down(s2,  off);
        sp  += __shfl_down(sp,  off);
        sp2 += __shfl_down(sp2, off);
    }
    __shared__ float red[16];
    int lane = tid & 63, wid = tid >> 6;
    if (lane == 0) { red[wid] = s; red[4 + wid] = s2; red[8 + wid] = sp; red[12 + wid] = sp2; }
    __syncthreads();
    s   = red[0] + red[1] + red[2] + red[3];
    s2  = red[4] + red[5] + red[6] + red[7];
    sp  = red[8] + red[9] + red[10] + red[11];
    sp2 = red[12] + red[13] + red[14] + red[15];

    float mean  = s * (1.0f / C_DIM);
    float inv   = rsqrtf(s2 * (1.0f / C_DIM) - mean * mean + 1e-5f);
    float meanp = sp * (1.0f / C_DIM);
    float invp  = rsqrtf(sp2 * (1.0f / C_DIM) - meanp * meanp + 1e-5f);

    float4 gv = ((const float4*)g)[tid];
    float4 bv = ((const float4*)b)[tid];
    float4 hv, hp;
    hv.x = (v.x - mean) * inv * gv.x + bv.x;
    hv.y = (v.y - mean) * inv * gv.y + bv.y;
    hv.z = (v.z - mean) * inv * gv.z + bv.z;
    hv.w = (v.w - mean) * inv * gv.w + bv.w;
    if (t != 0) {
        hp.x = (vp.x - meanp) * invp * gv.x + bv.x;
        hp.y = (vp.y - meanp) * invp * gv.y + bv.y;
        hp.z = (vp.z - meanp) * invp * gv.z + bv.z;
        hp.w = (vp.w - meanp) * invp * gv.w + bv.w;
    } else {
        hp = make_float4(0.f, 0.f, 0.f, 0.f);
    }

    float4 m1 = ((const float4*)mk)[tid];
    bf16x4 o;
    o.x = (bf16)(hp.x + m1.x * (hv.x - hp.x));
    o.y = (bf16)(hp.y + m1.y * (hv.y - hp.y));
    o.z = (bf16)(hp.z + m1.z * (hv.z - hp.z));
    o.w = (bf16)(hp.w + m1.w * (hv.w - hp.w));
    ((bf16x4*)xk)[i4] = o;

    if (HASV) {
        float4 m2 = ((const float4*)mv)[tid];
        o.x = (bf16)(hp.x + m2.x * (hv.x - hp.x));
        o.y = (bf16)(hp.y + m2.y * (hv.y - hp.y));
        o.z = (bf16)(hp.z + m2.z * (hv.z - hp.z));
        o.w = (bf16)(hp.w + m2.w * (hv.w - hp.w));
        ((bf16x4*)xv)[i4] = o;
    }

    float4 m3 = ((const float4*)mr)[tid];
    o.x = (bf16)(hp.x + m3.x * (hv.x - hp.x));
    o.y = (bf16)(hp.y + m3.y * (hv.y - hp.y));
    o.z = (bf16)(hp.z + m3.z * (hv.z - hp.z));
    o.w = (bf16)(hp.w + m3.w * (hv.w - hp.w));
    ((bf16x4*)xr)[i4] = o;
}

// pre_kernel: blocks [0,NROWS) = lnmix1; blocks [NROWS, NROWS+13312) = f2b7.
// Merging saves one dispatch boundary (~10us gap); both depend only on inputs.
struct PreArgs {
    W7 w;
    const float *x, *g, *b, *mk, *mv, *mr;
    bf16 *xk, *xv, *xr;
};

__global__ __launch_bounds__(256) void pre_kernel(PreArgs a)
{
    int blk = blockIdx.x, tid = threadIdx.x;
    if (blk < NROWS) {
        lnmix_body<true>(blk, tid, a.x, a.g, a.b, a.mk, a.mv, a.mr, a.xk, a.xv, a.xr);
    } else {
        int id = (blk - NROWS) * 256 + tid;
        int seg = 0;
#pragma unroll
        for (int j = 1; j < 7; ++j) if (id >= a.w.cum[j]) seg = j;
        int i = id - a.w.cum[seg];
        float4 v = ((const float4*)a.w.s[seg])[i];
        bf16x4 o = { (bf16)v.x, (bf16)v.y, (bf16)v.z, (bf16)v.w };
        ((bf16x4*)a.w.d[seg])[i] = o;
    }
}

__global__ __launch_bounds__(256) void lnmix_kernel(const float* __restrict__ x,
                                                    const float* __restrict__ g,
                                                    const float* __restrict__ b,
                                                    const float* __restrict__ mk,
                                                    const float* __restrict__ mr,
                                                    bf16* __restrict__ xk,
                                                    bf16* __restrict__ xr)
{
    lnmix_body<false>(blockIdx.x, threadIdx.x, x, g, b, mk, nullptr, mr, xk, nullptr, xr);
}

// ---------------------------------------------------------------------------
// gemm_p: 256x128, BK=64, 512 thr (8 waves 4m x 2n), triple-buffered mod-3
// LDS, counted vmcnt(6) at tile top (round-8 structure, best measured).
// NOW BATCHED (up to 3 problems per dispatch, block-range select). Unlike
// round-2's thrashing batch (n-striped, interleaved), each problem here is
// exactly 256 blocks = one full CU-wave, m-striped -> CUs run the problems
// SEQUENTIALLY, per-XCD L2 working sets never mix.
// Grid mapping: N=1024 m-striped XCDs (A-heavy; round-7: FETCH 3.3x lower);
// N=4096 n-striped.
// Epilogues (runtime, uniform): 0=none 1=sigmoid 2=relu^2 3=X2+acc 4=X2+S*acc
// ---------------------------------------------------------------------------
#define EPI_NONE 0
#define EPI_SIG 1
#define EPI_RELU2 2
#define EPI_ADD 3
#define EPI_SCALEADD 4

struct GemmArgs {
    const bf16* A;
    const bf16* W;
    void*       Y;
    const float* X2;
    const bf16*  S;
    int N, K, epi, outBf16;
};
struct GB3 { GemmArgs p[3]; int cum1, cum2; };
struct GB2 { GemmArgs p[2]; int cut; };

__global__ __launch_bounds__(512) void gemm_p(GB3 bt)
{
    // per-buffer: A 256x64 bf16 = 16384 ushorts (32KB), B 128x64 = 8192 (16KB)
    __shared__ unsigned short As[3 * 16384];   // 96 KB
    __shared__ unsigned short Bs[3 * 8192];    // 48 KB

    int tid = threadIdx.x;
    int id  = blockIdx.x;
    int pi  = (id >= bt.cum1) + (id >= bt.cum2);       // block-uniform
    const bf16* PA = bt.p[pi].A;
    const bf16* PW = bt.p[pi].W;
    void*       PY = bt.p[pi].Y;
    const float* PX2 = bt.p[pi].X2;
    const bf16*  PS  = bt.p[pi].S;
    int N = bt.p[pi].N, K = bt.p[pi].K;
    int epi = bt.p[pi].epi, obf = bt.p[pi].outBf16;
    int lid = id - (pi == 0 ? 0 : (pi == 1 ? bt.cum1 : bt.cum2));

    // Tile mapping. HW round-robins blockIdx across XCDs: xcd = lid & 7
    // (problem offsets are multiples of 256, so lid&7 == id&7).
    int ntn = N >> 7;                       // n-tiles: 8 (N=1024) or 32 (4096)
    int m_t, n_t;
    if (ntn == 8) {
        int xcd = lid & 7, s = lid >> 3;    // s in [0,32)
        n_t = s & 7;
        m_t = (xcd << 2) | (s >> 3);
    } else {
        int sq = lid >> 3;                  // [0,128)
        n_t = (lid & 7) * 4 + (sq & 3);
        m_t = sq >> 2;
    }
    int m0 = m_t * 256, n0 = n_t * 128;

    int wv = tid >> 6;                      // 0..7
    int ln = tid & 63;

    int srow = wv * 16 + (ln >> 2);                    // 0..127
    int qsw  = ((ln & 3) - ((srow >> 1) & 3)) & 3;     // rotated k-quad
    const bf16* Ag = PA + (size_t)(m0 + srow) * K + qsw * 8;
    const bf16* Wg = PW + (size_t)(n0 + srow) * K + qsw * 8;
    size_t rowK128 = (size_t)128 * K;

    unsigned short* AsW = As + wv * 512;
    unsigned short* BsW = Bs + wv * 512;

    int wm = (wv & 3) * 64, wn = (wv >> 2) * 64;
    int ra0 = wm + (ln & 15);
    int rb0 = wn + (ln & 15);
    int qa  = ln >> 4;
    int abase = ra0 * 32 + (((qa + ((ra0 >> 1) & 3)) & 3) * 8);
    int bbase = rb0 * 32 + (((qa + ((rb0 >> 1) & 3)) & 3) * 8);

    floatx4 acc[4][4] = {};

#define STAGE_A(kt, bi)                                                       \
    do {                                                                      \
        const bf16* _a = Ag + (size_t)(kt) * 64;                              \
        unsigned short* _d = AsW + (bi) * 16384;                              \
        GLDS(_a,                _d);                                          \
        GLDS(_a + rowK128,      _d + 4096);                                   \
        GLDS(_a + 32,           _d + 8192);                                   \
        GLDS(_a + rowK128 + 32, _d + 12288);                                  \
    } while (0)
#define STAGE_B(kt, bi)                                                       \
    do {                                                                      \
        const bf16* _b = Wg + (size_t)(kt) * 64;                              \
        unsigned short* _d = BsW + (bi) * 8192;                               \
        GLDS(_b,      _d);                                                    \
        GLDS(_b + 32, _d + 4096);                                             \
    } while (0)

#define MFMA16(a, b)                                                          \
    do {                                                                      \
        _Pragma("unroll")                                                     \
        for (int i = 0; i < 4; ++i)                                           \
            _Pragma("unroll")                                                 \
            for (int j = 0; j < 4; ++j)                                       \
                acc[i][j] = __builtin_amdgcn_mfma_f32_16x16x32_bf16(          \
                    a[i], b[j], acc[i][j], 0, 0, 0);                          \
    } while (0)

    int nt = K >> 6;                        // 16 (K=1024) or 64 (K=4096)

    STAGE_A(0, 0); STAGE_B(0, 0);
    STAGE_A(1, 1); STAGE_B(1, 1);

    int bi = 0, bi2 = 2;                    // read buffer, stage buffer
    for (int t = 0; t < nt; ++t) {
        if (t < nt - 1) asm volatile("s_waitcnt vmcnt(6)" ::: "memory");
        else            asm volatile("s_waitcnt vmcnt(0)" ::: "memory");
        __builtin_amdgcn_s_barrier();        // all waves: tile t landed,
        __builtin_amdgcn_sched_barrier(0);   // and t-1 reads fully done

        const unsigned short* A0 = As + bi * 16384 + abase;
        const unsigned short* B0 = Bs + bi * 8192  + bbase;
        int dost = (t + 2 < nt);

        bf16x8 a[4], b[4];
#pragma unroll
        for (int i = 0; i < 4; ++i) a[i] = *(const bf16x8*)(A0 + i * 512);
#pragma unroll
        for (int j = 0; j < 4; ++j) b[j] = *(const bf16x8*)(B0 + j * 512);
        if (dost) STAGE_A(t + 2, bi2);
        asm volatile("s_waitcnt lgkmcnt(0)" ::: "memory");
        __builtin_amdgcn_sched_barrier(0);   // rule 18
        MFMA16(a, b);

#pragma unroll
        for (int i = 0; i < 4; ++i) a[i] = *(const bf16x8*)(A0 + 8192 + i * 512);
#pragma unroll
        for (int j = 0; j < 4; ++j) b[j] = *(const bf16x8*)(B0 + 4096 + j * 512);
        if (dost) STAGE_B(t + 2, bi2);
        asm volatile("s_waitcnt lgkmcnt(0)" ::: "memory");
        __builtin_amdgcn_sched_barrier(0);
        MFMA16(a, b);

        bi  = (bi  == 2) ? 0 : bi  + 1;
        bi2 = (bi2 == 2) ? 0 : bi2 + 1;
    }

#undef STAGE_A
#undef STAGE_B
#undef MFMA16

    int row0 = (ln >> 4) * 4;
    int colb = n0 + wn + (ln & 15);
#pragma unroll
    for (int i = 0; i < 4; ++i) {
        int gm = m0 + wm + i * 16 + row0;
#pragma unroll
        for (int j = 0; j < 4; ++j) {
            int gn = colb + j * 16;
#pragma unroll
            for (int r = 0; r < 4; ++r) {
                size_t idx = (size_t)(gm + r) * N + gn;
                float v = acc[i][j][r];
                if (epi == EPI_SIG)        v = 1.0f / (1.0f + __expf(-v));
                else if (epi == EPI_RELU2) { float t2 = fmaxf(v, 0.0f); v = t2 * t2; }
                else if (epi == EPI_ADD)   v = PX2[idx] + v;
                else if (epi == EPI_SCALEADD) v = PX2[idx] + (float)PS[idx] * v;
                if (obf) ((bf16*)PY)[idx] = (bf16)v;
                else     ((float*)PY)[idx] = v;
            }
        }
    }
}

// ---------------------------------------------------------------------------
// gemm_w: 256x256 tile, BK=64, 512 thr (8 waves, 2m x 4n of 128x64 each),
// double-buffered 128KB LDS (round-10 structure; improved FFN-up).
// NOW BATCHED (2 problems): ffn-up (N=4096, 512 blocks n-striped) + sr2
// (N=1024, 128 blocks m-striped) in one dispatch.
// ---------------------------------------------------------------------------
__global__ __launch_bounds__(512) void gemm_w(GB2 bt)
{
    __shared__ unsigned short As[2 * 16384];   // 64 KB
    __shared__ unsigned short Bs[2 * 16384];   // 64 KB

    int tid = threadIdx.x;
    int id  = blockIdx.x;
    int pi  = (id >= bt.cut);
    const bf16* PA = bt.p[pi].A;
    const bf16* PW = bt.p[pi].W;
    void*       PY = bt.p[pi].Y;
    int N = bt.p[pi].N, K = bt.p[pi].K;
    int epi = bt.p[pi].epi, obf = bt.p[pi].outBf16;
    int lid = pi ? (id - bt.cut) : id;

    int ntn = N >> 8;                       // 256-wide n-tiles: 16 or 4
    int m_t, n_t;
    if (ntn == 16) {
        int sq = lid >> 3;                  // [0,64)
        n_t = (lid & 7) * 2 + (sq & 1);
        m_t = sq >> 1;                      // [0,32)
    } else {
        int xcd = lid & 7, s = lid >> 3;    // s in [0,16)
        n_t = s & 3;
        m_t = (xcd << 2) | (s >> 2);        // [0,32)
    }
    int m0 = m_t * 256, n0 = n_t * 256;

    int wv = tid >> 6;                      // 0..7
    int ln = tid & 63;

    int srow = wv * 16 + (ln >> 2);                    // 0..127
    int qsw  = ((ln & 3) - ((srow >> 1) & 3)) & 3;
    const bf16* Ag = PA + (size_t)(m0 + srow) * K + qsw * 8;
    const bf16* Wg = PW + (size_t)(n0 + srow) * K + qsw * 8;
    size_t rowK128 = (size_t)128 * K;

    unsigned short* AsW = As + wv * 512;
    unsigned short* BsW = Bs + wv * 512;

    // wave: m-slot (wv>>2) of 2 x 128 rows; n-slot (wv&3) of 4 x 64 cols
    int wm = (wv >> 2) * 128, wn = (wv & 3) * 64;
    int ra0 = wm + (ln & 15);
    int rb0 = wn + (ln & 15);
    int qa  = ln >> 4;
    int abase = ra0 * 32 + (((qa + ((ra0 >> 1) & 3)) & 3) * 8);
    int bbase = rb0 * 32 + (((qa + ((rb0 >> 1) & 3)) & 3) * 8);

    floatx4 acc[8][4] = {};

#define WSTAGE(kt, bi)                                                        \
    do {                                                                      \
        const bf16* _a = Ag + (size_t)(kt) * 64;                              \
        const bf16* _b = Wg + (size_t)(kt) * 64;                              \
        unsigned short* _dA = AsW + (bi) * 16384;                             \
        unsigned short* _dB = BsW + (bi) * 16384;                             \
        GLDS(_a,                _dA);                                         \
        GLDS(_a + rowK128,      _dA + 4096);                                  \
        GLDS(_a + 32,           _dA + 8192);                                  \
        GLDS(_a + rowK128 + 32, _dA + 12288);                                 \
        GLDS(_b,                _dB);                                         \
        GLDS(_b + rowK128,      _dB + 4096);                                  \
        GLDS(_b + 32,           _dB + 8192);                                  \
        GLDS(_b + rowK128 + 32, _dB + 12288);                                 \
    } while (0)

    int nt = K >> 6;                        // 16 for K=1024

    WSTAGE(0, 0);
    asm volatile("s_waitcnt vmcnt(0)" ::: "memory");
    __builtin_amdgcn_s_barrier();
    __builtin_amdgcn_sched_barrier(0);

    for (int t = 0; t < nt; ++t) {
        int bi = t & 1;
        if (t + 1 < nt) WSTAGE(t + 1, bi ^ 1);     // 8 GLDS fly under compute

        const unsigned short* A0 = As + bi * 16384 + abase;
        const unsigned short* B0 = Bs + bi * 16384 + bbase;

#pragma unroll
        for (int s = 0; s < 2; ++s) {
            bf16x8 a[8], b[4];
#pragma unroll
            for (int i = 0; i < 8; ++i) a[i] = *(const bf16x8*)(A0 + s * 8192 + i * 512);
#pragma unroll
            for (int j = 0; j < 4; ++j) b[j] = *(const bf16x8*)(B0 + s * 8192 + j * 512);
            asm volatile("s_waitcnt lgkmcnt(0)" ::: "memory");
            __builtin_amdgcn_sched_barrier(0);     // rule 18
#pragma unroll
            for (int i = 0; i < 8; ++i)
#pragma unroll
                for (int j = 0; j < 4; ++j)
                    acc[i][j] = __builtin_amdgcn_mfma_f32_16x16x32_bf16(
                        a[i], b[j], acc[i][j], 0, 0, 0);
        }

        asm volatile("s_waitcnt vmcnt(0)" ::: "memory");
        __builtin_amdgcn_s_barrier();
        __builtin_amdgcn_sched_barrier(0);
    }
#undef WSTAGE

    int row0 = (ln >> 4) * 4;
    int colb = n0 + wn + (ln & 15);
#pragma unroll
    for (int i = 0; i < 8; ++i) {
        int gm = m0 + wm + i * 16 + row0;
#pragma unroll
        for (int j = 0; j < 4; ++j) {
            int gn = colb + j * 16;
#pragma unroll
            for (int r = 0; r < 4; ++r) {
                size_t idx = (size_t)(gm + r) * N + gn;
                float v = acc[i][j][r];
                if (epi == EPI_RELU2) { float t2 = fmaxf(v, 0.0f); v = t2 * t2; }
                else if (epi == EPI_SIG) v = 1.0f / (1.0f + __expf(-v));
                if (obf) ((bf16*)PY)[idx] = (bf16)v;
                else     ((float*)PY)[idx] = v;
            }
        }
    }
}

// ---------------------------------------------------------------------------
// WKV segmented scan, now 2 passes: wkv_seg (per-segment summaries) and
// wkv_out2 (per-segment output; folds the old wkv_comb in -- each block
// scans the <=31 predecessor summaries itself: ~31 coalesced loads + short
// FMA/exp chain, cheaper than a dispatch boundary).
// ---------------------------------------------------------------------------
__global__ __launch_bounds__(256) void wkv_seg(const float* __restrict__ k,
                                               const float* __restrict__ v,
                                               const float* __restrict__ decay,
                                               float* __restrict__ sa,
                                               float* __restrict__ sb,
                                               float* __restrict__ sp)
{
    int idx = blockIdx.x * 256 + threadIdx.x;   // (b*NSEG+seg)*C + c
    int c   = idx & (C_DIM - 1);
    int bs  = idx >> 10;
    int seg = bs & (NSEG - 1);
    int b   = bs >> 5;
    float w = -__expf(decay[c]);
    size_t base = ((size_t)b * T_DIM + (size_t)seg * SEGL) * C_DIM + c;
    float aa = 0.f, bb = 0.f, pp = -1e38f;
    for (int t = 0; t < SEGL; ++t) {
        size_t off = base + (size_t)t * C_DIM;
        float kk = k[off], vv = v[off];
        float ww2 = pp + w;
        float p2  = fmaxf(ww2, kk);
        float e1  = __expf(ww2 - p2);
        float e2  = __expf(kk - p2);
        aa = e1 * aa + e2 * vv;
        bb = e1 * bb + e2;
        pp = p2;
    }
    sa[idx] = aa; sb[idx] = bb; sp[idx] = pp;
}

__global__ __launch_bounds__(256) void wkv_out2(const float* __restrict__ k,
                                                const float* __restrict__ v,
                                                const bf16* __restrict__ sr,
                                                const float* __restrict__ decay,
                                                const float* __restrict__ first,
                                                const float* __restrict__ sa,
                                                const float* __restrict__ sb,
                                                const float* __restrict__ sp,
                                                bf16* __restrict__ out)
{
    int idx = blockIdx.x * 256 + threadIdx.x;   // (b*NSEG+seg)*C + c
    int c   = idx & (C_DIM - 1);
    int bs  = idx >> 10;
    int seg = bs & (NSEG - 1);
    int b   = bs >> 5;
    float w = -__expf(decay[c]);
    float u = first[c];

    // incoming state: scan predecessor segment summaries (was wkv_comb)
    float wL = w * (float)SEGL;
    float aa = 0.f, bb = 0.f, pp = -1e38f;
    size_t sbase = (size_t)b * NSEG * C_DIM + c;
    for (int j = 0; j < seg; ++j) {
        size_t o = sbase + (size_t)j * C_DIM;
        float a_s = sa[o], b_s = sb[o], p_s = sp[o];
        float pd = pp + wL;
        float pn = fmaxf(pd, p_s);
        float e1 = __expf(pd - pn);
        float e2 = __expf(p_s - pn);
        aa = e1 * aa + e2 * a_s;
        bb = e1 * bb + e2 * b_s;
        pp = pn;
    }

    size_t base = ((size_t)b * T_DIM + (size_t)seg * SEGL) * C_DIM + c;
    for (int t = 0; t < SEGL; ++t) {
        size_t off = base + (size_t)t * C_DIM;
        float kk = k[off], vv = v[off];
        float ww = u + kk;
        float p  = fmaxf(pp, ww);
        float e1 = __expf(pp - p);
        float e2 = __expf(ww - p);
        float o  = (e1 * aa + e2 * vv) / (e1 * bb + e2);
        out[off] = (bf16)((float)sr[off] * o);
        float ww2 = pp + w;
        float p2  = fmaxf(ww2, kk);
        float e1b = __expf(ww2 - p2);
        float e2b = __expf(kk - p2);
        aa = e1b * aa + e2b * vv;
        bb = e1b * bb + e2b;
        pp = p2;
    }
}

// ---------------------------------------------------------------------------
// Orchestration: 8 dispatches (was 13; ~10us boundary cost each).
//   1 pre (f2b7+lnmix1)   2 gemm_p{k,v,sr}   3 wkv_seg   4 wkv_out2
//   5 gemm_p{ow}          6 lnmix2           7 gemm_w{ffn-up,sr2}
//   8 gemm_p{ffn-down}
// Workspace (byte offsets, 173 MiB peak):
//   [0,26M)    bf16 weights
//   [26,74M)   bf16 acts: xk xv xr -> rwkv | xk2 xr2 sr2
//   [74,170M)  fp32 k (32M), v (32M), sr_b bf16 (16M @138M), kk_b (64M @106M)
//   [170,173M) WKV scan scratch: 3 x 512 KiB (sa,sb,sp)
// ---------------------------------------------------------------------------
extern "C" void kernel_launch(void* const* d_in, const int* in_sizes, int n_in,
                              void* d_out, int out_size, void* d_ws, size_t ws_size,
                              hipStream_t stream)
{
    const float* x          = (const float*)d_in[0];
    const float* ln1_w      = (const float*)d_in[1];
    const float* ln1_b      = (const float*)d_in[2];
    const float* ln2_w      = (const float*)d_in[3];
    const float* ln2_b      = (const float*)d_in[4];
    const float* time_decay = (const float*)d_in[5];
    const float* time_first = (const float*)d_in[6];
    const float* tmk        = (const float*)d_in[7];
    const float* tmv        = (const float*)d_in[8];
    const float* tmr        = (const float*)d_in[9];
    const float* att_kw     = (const float*)d_in[10];
    const float* att_vw     = (const float*)d_in[11];
    const float* att_rw     = (const float*)d_in[12];
    const float* att_ow     = (const float*)d_in[13];
    const float* f_tmk      = (const float*)d_in[14];
    const float* f_tmr      = (const float*)d_in[15];
    const float* f_kw       = (const float*)d_in[16];
    const float* f_rw       = (const float*)d_in[17];
    const float* f_vw       = (const float*)d_in[18];
    float* out = (float*)d_out;

    char* W8 = (char*)d_ws;
    bf16* kw_b  = (bf16*)(W8 + 0 * MB);
    bf16* vw_b  = (bf16*)(W8 + 2 * MB);
    bf16* rw_b  = (bf16*)(W8 + 4 * MB);
    bf16* ow_b  = (bf16*)(W8 + 6 * MB);
    bf16* fkw_b = (bf16*)(W8 + 8 * MB);
    bf16* frw_b = (bf16*)(W8 + 16 * MB);
    bf16* fvw_b = (bf16*)(W8 + 18 * MB);

    bf16*  xk_b   = (bf16*)(W8 + 26 * MB);
    bf16*  xv_b   = (bf16*)(W8 + 42 * MB);
    bf16*  xr_b   = (bf16*)(W8 + 58 * MB);
    bf16*  rwkv_b = xk_b;
    bf16*  xk2_b  = (bf16*)(W8 + 26 * MB);
    bf16*  xr2_b  = (bf16*)(W8 + 42 * MB);
    bf16*  sr2_b  = (bf16*)(W8 + 58 * MB);
    float* kbuf   = (float*)(W8 + 74 * MB);
    float* vbuf   = (float*)(W8 + 106 * MB);
    bf16*  srb_b  = (bf16*)(W8 + 138 * MB);     // 16 MiB
    bf16*  kk_b   = (bf16*)(W8 + 106 * MB);     // 64 MiB, overlaps vbuf; kk is
    // written only AFTER wkv_out2 has consumed kbuf/vbuf (ChannelMix phase).

    size_t KB512 = (size_t)512 * 1024;
    float* sc_a = (float*)(W8 + 170 * MB);
    float* sc_b = (float*)(W8 + 170 * MB + 1 * KB512);
    float* sc_p = (float*)(W8 + 170 * MB + 2 * KB512);

    // ---- dispatch 1: weight conversion + lnmix1 fused ----
    int nC4 = C_DIM * C_DIM / 4, nF4 = FFN_DIM * C_DIM / 4;
    PreArgs pa;
    const float* srcs[7] = { att_kw, att_vw, att_rw, att_ow, f_kw, f_rw, f_vw };
    bf16*        dsts[7] = { kw_b, vw_b, rw_b, ow_b, fkw_b, frw_b, fvw_b };
    int          cnts[7] = { nC4, nC4, nC4, nC4, nF4, nC4, nF4 };
    int cum = 0;
    for (int i = 0; i < 7; ++i) { pa.w.s[i] = srcs[i]; pa.w.d[i] = dsts[i]; pa.w.cum[i] = cum; cum += cnts[i]; }
    pa.w.cum[7] = cum;                                 // 3407872, /256 = 13312
    pa.x = x; pa.g = ln1_w; pa.b = ln1_b; pa.mk = tmk; pa.mv = tmv; pa.mr = tmr;
    pa.xk = xk_b; pa.xv = xv_b; pa.xr = xr_b;
    pre_kernel<<<NROWS + cum / 256, 256, 0, stream>>>(pa);

    auto prob = [](const bf16* A, const bf16* W, void* Y, const float* X2,
                   const bf16* S, int N, int K, int epi, int obf) {
        GemmArgs p; p.A = A; p.W = W; p.Y = Y; p.X2 = X2; p.S = S;
        p.N = N; p.K = K; p.epi = epi; p.outBf16 = obf; return p;
    };
    auto launch1 = [&](GemmArgs p, int grid) {       // single-problem gemm_p
        GB3 b; b.p[0] = p; b.p[1] = p; b.p[2] = p; b.cum1 = grid; b.cum2 = grid;
        gemm_p<<<grid, 512, 0, stream>>>(b);
    };

    int segGrid = B_DIM * NSEG * C_DIM / 256;   // 512

    // ---- dispatch 2: k, v, sr batched (3 x 256 blocks, sequential CU-waves)
    {
        GB3 b;
        b.p[0] = prob(xk_b, kw_b, kbuf,  nullptr, nullptr, C_DIM, C_DIM, EPI_NONE, 0);
        b.p[1] = prob(xv_b, vw_b, vbuf,  nullptr, nullptr, C_DIM, C_DIM, EPI_NONE, 0);
        b.p[2] = prob(xr_b, rw_b, srb_b, nullptr, nullptr, C_DIM, C_DIM, EPI_SIG,  1);
        b.cum1 = 256; b.cum2 = 512;
        gemm_p<<<768, 512, 0, stream>>>(b);
    }
    // ---- dispatches 3-4: WKV ----
    wkv_seg<<<segGrid, 256, 0, stream>>>(kbuf, vbuf, time_decay, sc_a, sc_b, sc_p);
    wkv_out2<<<segGrid, 256, 0, stream>>>(kbuf, vbuf, srb_b, time_decay, time_first,
                                          sc_a, sc_b, sc_p, rwkv_b);
    // ---- dispatch 5: output projection ----
    launch1(prob(rwkv_b, ow_b, out, x, nullptr, C_DIM, C_DIM, EPI_ADD, 0), 256);

    // ---- dispatch 6: lnmix2 ----
    lnmix_kernel<<<NROWS, 256, 0, stream>>>(out, ln2_w, ln2_b, f_tmk, f_tmr,
                                            xk2_b, xr2_b);
    // ---- dispatch 7: FFN-up (256² n-striped) + sr2 (256² m-striped) ----
    {
        GB2 b;
        b.p[0] = prob(xk2_b, fkw_b, kk_b,  nullptr, nullptr, FFN_DIM, C_DIM, EPI_RELU2, 1);
        b.p[1] = prob(xr2_b, frw_b, sr2_b, nullptr, nullptr, C_DIM,   C_DIM, EPI_SIG,   1);
        b.cut = (NROWS / 256) * (FFN_DIM / 256);     // 512
        gemm_w<<<b.cut + (NROWS / 256) * (C_DIM / 256), 512, 0, stream>>>(b);
    }
    // ---- dispatch 8: FFN-down ----
    launch1(prob(kk_b, fvw_b, out, out, sr2_b, C_DIM, FFN_DIM, EPI_SCALEADD, 0), 256);
}

// Round 13
// 543.729 us; speedup vs baseline: 1.0005x; 1.0005x over previous
//
#include <hip/hip_runtime.h>
#include <cstdint>

#define C_DIM 1024
#define T_DIM 2048
#define B_DIM 4
#define FFN_DIM 4096
#define NROWS (B_DIM * T_DIM)                 // 8192 rows (B*T)
#define NELEM ((size_t)NROWS * C_DIM)
#define MB ((size_t)1 << 20)
#define NSEG 32
#define SEGL (T_DIM / NSEG)                   // 64

typedef __bf16 bf16;
typedef __bf16 bf16x4 __attribute__((ext_vector_type(4)));
typedef __bf16 bf16x8 __attribute__((ext_vector_type(8)));
typedef float  floatx4 __attribute__((ext_vector_type(4)));

// async global->LDS, 16B per lane; LDS dest is wave-uniform base + lane*16
#define GLDS(g, l) __builtin_amdgcn_global_load_lds(                          \
    (const __attribute__((address_space(1))) void*)(g),                       \
    (__attribute__((address_space(3))) void*)(l), 16, 0, 0)

// ---------------------------------------------------------------------------
// All 7 weight fp32->bf16 conversions in ONE dispatch.
// ---------------------------------------------------------------------------
struct W7 {
    const float* s[7];
    bf16*        d[7];
    int          cum[8];   // cumulative float4 counts, cum[7] = total
};

__global__ __launch_bounds__(256) void f2b7_kernel(W7 w)
{
    int id = blockIdx.x * 256 + threadIdx.x;
    int seg = 0;
#pragma unroll
    for (int j = 1; j < 7; ++j) if (id >= w.cum[j]) seg = j;
    int i = id - w.cum[seg];
    float4 v = ((const float4*)w.s[seg])[i];
    bf16x4 o = { (bf16)v.x, (bf16)v.y, (bf16)v.z, (bf16)v.w };
    ((bf16x4*)w.d[seg])[i] = o;
}

// ---------------------------------------------------------------------------
// Fused LayerNorm + token-shift mix. One block per row t; computes LN stats
// for rows t and t-1 (recompute, memory-bound), emits bf16 mixed operands.
// hx = LN(x[t-1]) (zero row at t==0, matching reference pad-before-shift).
// ---------------------------------------------------------------------------
template<bool HASV>
__global__ __launch_bounds__(256) void lnmix_kernel(const float* __restrict__ x,
                                                    const float* __restrict__ g,
                                                    const float* __restrict__ b,
                                                    const float* __restrict__ mk,
                                                    const float* __restrict__ mv,
                                                    const float* __restrict__ mr,
                                                    bf16* __restrict__ xk,
                                                    bf16* __restrict__ xv,
                                                    bf16* __restrict__ xr)
{
    int row = blockIdx.x;
    int t   = row & (T_DIM - 1);
    int tid = threadIdx.x;
    size_t i4 = (size_t)row * 256 + tid;

    float4 v  = ((const float4*)x)[i4];
    float4 vp = make_float4(0.f, 0.f, 0.f, 0.f);
    if (t != 0) vp = ((const float4*)x)[i4 - 256];

    float s   = v.x + v.y + v.z + v.w;
    float s2  = v.x * v.x + v.y * v.y + v.z * v.z + v.w * v.w;
    float sp  = vp.x + vp.y + vp.z + vp.w;
    float sp2 = vp.x * vp.x + vp.y * vp.y + vp.z * vp.z + vp.w * vp.w;
    for (int off = 32; off > 0; off >>= 1) {
        s   += __shfl_down(s,   off);
        s2  += __shfl_down(s2,  off);
        sp  += __shfl_down(sp,  off);
        sp2 += __shfl_down(sp2, off);
    }
    __shared__ float red[16];
    int lane = tid & 63, wid = tid >> 6;
    if (lane == 0) { red[wid] = s; red[4 + wid] = s2; red[8 + wid] = sp; red[12 + wid] = sp2; }
    __syncthreads();
    s   = red[0] + red[1] + red[2] + red[3];
    s2  = red[4] + red[5] + red[6] + red[7];
    sp  = red[8] + red[9] + red[10] + red[11];
    sp2 = red[12] + red[13] + red[14] + red[15];

    float mean  = s * (1.0f / C_DIM);
    float inv   = rsqrtf(s2 * (1.0f / C_DIM) - mean * mean + 1e-5f);
    float meanp = sp * (1.0f / C_DIM);
    float invp  = rsqrtf(sp2 * (1.0f / C_DIM) - meanp * meanp + 1e-5f);

    float4 gv = ((const float4*)g)[tid];
    float4 bv = ((const float4*)b)[tid];
    float4 hv, hp;
    hv.x = (v.x - mean) * inv * gv.x + bv.x;
    hv.y = (v.y - mean) * inv * gv.y + bv.y;
    hv.z = (v.z - mean) * inv * gv.z + bv.z;
    hv.w = (v.w - mean) * inv * gv.w + bv.w;
    if (t != 0) {
        hp.x = (vp.x - meanp) * invp * gv.x + bv.x;
        hp.y = (vp.y - meanp) * invp * gv.y + bv.y;
        hp.z = (vp.z - meanp) * invp * gv.z + bv.z;
        hp.w = (vp.w - meanp) * invp * gv.w + bv.w;
    } else {
        hp = make_float4(0.f, 0.f, 0.f, 0.f);
    }

    float4 m1 = ((const float4*)mk)[tid];
    bf16x4 o;
    o.x = (bf16)(hp.x + m1.x * (hv.x - hp.x));
    o.y = (bf16)(hp.y + m1.y * (hv.y - hp.y));
    o.z = (bf16)(hp.z + m1.z * (hv.z - hp.z));
    o.w = (bf16)(hp.w + m1.w * (hv.w - hp.w));
    ((bf16x4*)xk)[i4] = o;

    if (HASV) {
        float4 m2 = ((const float4*)mv)[tid];
        o.x = (bf16)(hp.x + m2.x * (hv.x - hp.x));
        o.y = (bf16)(hp.y + m2.y * (hv.y - hp.y));
        o.z = (bf16)(hp.z + m2.z * (hv.z - hp.z));
        o.w = (bf16)(hp.w + m2.w * (hv.w - hp.w));
        ((bf16x4*)xv)[i4] = o;
    }

    float4 m3 = ((const float4*)mr)[tid];
    o.x = (bf16)(hp.x + m3.x * (hv.x - hp.x));
    o.y = (bf16)(hp.y + m3.y * (hv.y - hp.y));
    o.z = (bf16)(hp.z + m3.z * (hv.z - hp.z));
    o.w = (bf16)(hp.w + m3.w * (hv.w - hp.w));
    ((bf16x4*)xr)[i4] = o;
}

// ---------------------------------------------------------------------------
// gemm_p: round-8 kernel VERBATIM (part of best measured 528.7us config).
// 256x128 tile, BK=64, 512 thr (8 waves 4m x 2n), triple-buffered mod-3
// LDS, counted vmcnt(6) at tile top.
// Grid: N=1024 -> 256 blocks, m-striped XCDs. N=4096 -> 1024, n-striped.
// Epilogues (runtime, uniform): 0=none 1=sigmoid 2=relu^2 3=X2+acc 4=X2+S*acc
// ---------------------------------------------------------------------------
#define EPI_NONE 0
#define EPI_SIG 1
#define EPI_RELU2 2
#define EPI_ADD 3
#define EPI_SCALEADD 4

struct GemmArgs {
    const bf16* A;
    const bf16* W;
    void*       Y;
    const float* X2;
    const bf16*  S;
    int N, K, epi, outBf16;
};

__global__ __launch_bounds__(512) void gemm_p(GemmArgs pr)
{
    // per-buffer: A 256x64 bf16 = 16384 ushorts (32KB), B 128x64 = 8192 (16KB)
    __shared__ unsigned short As[3 * 16384];   // 96 KB
    __shared__ unsigned short Bs[3 * 8192];    // 48 KB

    int tid = threadIdx.x;
    int lid = blockIdx.x;
    const bf16* PA = pr.A;
    const bf16* PW = pr.W;
    void*       PY = pr.Y;
    const float* PX2 = pr.X2;
    const bf16*  PS  = pr.S;
    int N = pr.N, K = pr.K;
    int epi = pr.epi, obf = pr.outBf16;

    int ntn = N >> 7;                       // n-tiles: 8 (N=1024) or 32 (4096)
    int m_t, n_t;
    if (ntn == 8) {
        int xcd = lid & 7, s = lid >> 3;    // s in [0,32)
        n_t = s & 7;
        m_t = (xcd << 2) | (s >> 3);
    } else {
        int sq = lid >> 3;                  // [0,128)
        n_t = (lid & 7) * 4 + (sq & 3);
        m_t = sq >> 2;
    }
    int m0 = m_t * 256, n0 = n_t * 128;

    int wv = tid >> 6;                      // 0..7
    int ln = tid & 63;

    int srow = wv * 16 + (ln >> 2);                    // 0..127
    int qsw  = ((ln & 3) - ((srow >> 1) & 3)) & 3;     // rotated k-quad
    const bf16* Ag = PA + (size_t)(m0 + srow) * K + qsw * 8;
    const bf16* Wg = PW + (size_t)(n0 + srow) * K + qsw * 8;
    size_t rowK128 = (size_t)128 * K;

    unsigned short* AsW = As + wv * 512;
    unsigned short* BsW = Bs + wv * 512;

    int wm = (wv & 3) * 64, wn = (wv >> 2) * 64;
    int ra0 = wm + (ln & 15);
    int rb0 = wn + (ln & 15);
    int qa  = ln >> 4;
    int abase = ra0 * 32 + (((qa + ((ra0 >> 1) & 3)) & 3) * 8);
    int bbase = rb0 * 32 + (((qa + ((rb0 >> 1) & 3)) & 3) * 8);

    floatx4 acc[4][4] = {};

#define STAGE_A(kt, bi)                                                       \
    do {                                                                      \
        const bf16* _a = Ag + (size_t)(kt) * 64;                              \
        unsigned short* _d = AsW + (bi) * 16384;                              \
        GLDS(_a,                _d);                                          \
        GLDS(_a + rowK128,      _d + 4096);                                   \
        GLDS(_a + 32,           _d + 8192);                                   \
        GLDS(_a + rowK128 + 32, _d + 12288);                                  \
    } while (0)
#define STAGE_B(kt, bi)                                                       \
    do {                                                                      \
        const bf16* _b = Wg + (size_t)(kt) * 64;                              \
        unsigned short* _d = BsW + (bi) * 8192;                               \
        GLDS(_b,      _d);                                                    \
        GLDS(_b + 32, _d + 4096);                                             \
    } while (0)

#define MFMA16(a, b)                                                          \
    do {                                                                      \
        _Pragma("unroll")                                                     \
        for (int i = 0; i < 4; ++i)                                           \
            _Pragma("unroll")                                                 \
            for (int j = 0; j < 4; ++j)                                       \
                acc[i][j] = __builtin_amdgcn_mfma_f32_16x16x32_bf16(          \
                    a[i], b[j], acc[i][j], 0, 0, 0);                          \
    } while (0)

    int nt = K >> 6;                        // 16 (K=1024) or 64 (K=4096)

    STAGE_A(0, 0); STAGE_B(0, 0);
    STAGE_A(1, 1); STAGE_B(1, 1);

    int bi = 0, bi2 = 2;                    // read buffer, stage buffer
    for (int t = 0; t < nt; ++t) {
        if (t < nt - 1) asm volatile("s_waitcnt vmcnt(6)" ::: "memory");
        else            asm volatile("s_waitcnt vmcnt(0)" ::: "memory");
        __builtin_amdgcn_s_barrier();        // all waves: tile t landed,
        __builtin_amdgcn_sched_barrier(0);   // and t-1 reads fully done

        const unsigned short* A0 = As + bi * 16384 + abase;
        const unsigned short* B0 = Bs + bi * 8192  + bbase;
        int dost = (t + 2 < nt);

        bf16x8 a[4], b[4];
#pragma unroll
        for (int i = 0; i < 4; ++i) a[i] = *(const bf16x8*)(A0 + i * 512);
#pragma unroll
        for (int j = 0; j < 4; ++j) b[j] = *(const bf16x8*)(B0 + j * 512);
        if (dost) STAGE_A(t + 2, bi2);
        asm volatile("s_waitcnt lgkmcnt(0)" ::: "memory");
        __builtin_amdgcn_sched_barrier(0);   // rule 18
        MFMA16(a, b);

#pragma unroll
        for (int i = 0; i < 4; ++i) a[i] = *(const bf16x8*)(A0 + 8192 + i * 512);
#pragma unroll
        for (int j = 0; j < 4; ++j) b[j] = *(const bf16x8*)(B0 + 4096 + j * 512);
        if (dost) STAGE_B(t + 2, bi2);
        asm volatile("s_waitcnt lgkmcnt(0)" ::: "memory");
        __builtin_amdgcn_sched_barrier(0);
        MFMA16(a, b);

        bi  = (bi  == 2) ? 0 : bi  + 1;
        bi2 = (bi2 == 2) ? 0 : bi2 + 1;
    }

#undef STAGE_A
#undef STAGE_B
#undef MFMA16

    int row0 = (ln >> 4) * 4;
    int colb = n0 + wn + (ln & 15);
#pragma unroll
    for (int i = 0; i < 4; ++i) {
        int gm = m0 + wm + i * 16 + row0;
#pragma unroll
        for (int j = 0; j < 4; ++j) {
            int gn = colb + j * 16;
#pragma unroll
            for (int r = 0; r < 4; ++r) {
                size_t idx = (size_t)(gm + r) * N + gn;
                float v = acc[i][j][r];
                if (epi == EPI_SIG)        v = 1.0f / (1.0f + __expf(-v));
                else if (epi == EPI_RELU2) { float t2 = fmaxf(v, 0.0f); v = t2 * t2; }
                else if (epi == EPI_ADD)   v = PX2[idx] + v;
                else if (epi == EPI_SCALEADD) v = PX2[idx] + (float)PS[idx] * v;
                if (obf) ((bf16*)PY)[idx] = (bf16)v;
                else     ((float*)PY)[idx] = v;
            }
        }
    }
}

// ---------------------------------------------------------------------------
// gemm_w: 256x256, BK=64, 512 thr (8 waves 2m x 4n of 128x64), 2-buf 128KB.
// m201-FAITHFUL 8-PHASE SCHEDULE (FFN-up only, N=4096/K=1024).
// 8 phases / 2 K-tiles: each phase {10-or-2 ds_read_b128 + one 2-GLDS
// half-stage -> lgkmcnt(0)+sched_barrier -> setprio(1) 16 MFMA setprio(0)}.
// Barrier + COUNTED vmcnt(8) only at odd phases (2 per K-tile, never 0
// mid-loop; m218: counted-vs-drain0 = T3's whole gain). Staging writes the
// sub-tile region freed exactly 2 phases earlier (ledger-verified);
// prefetch distance 5 phases (~2500cy >> 900cy HBM latency).
// Prologue = 12 GLDS (tile0 + tile1-sub0); last iteration peeled with
// waits {8,8,4,0}. Differs from round-9's failed fine-phase: 16-MFMA
// clusters (not 8), 2 barriers/K-tile (not 9), no vmcnt(0) drain.
// LDS layout/swizzle/read addressing identical to round-10 (BANK_CONFLICT=0).
// ---------------------------------------------------------------------------
__global__ __launch_bounds__(512) void gemm_w(GemmArgs pr)
{
    __shared__ unsigned short As[2 * 16384];   // 64 KB (2 buf x 256x64)
    __shared__ unsigned short Bs[2 * 16384];   // 64 KB

    int tid = threadIdx.x;
    int lid = blockIdx.x;
    const bf16* PA = pr.A;
    const bf16* PW = pr.W;
    void*       PY = pr.Y;
    int N = pr.N, K = pr.K;
    int epi = pr.epi, obf = pr.outBf16;

    // N=4096: 16 n-tiles, n-striped XCDs (2 per XCD); grid 512.
    int sq  = lid >> 3;                     // [0,64)
    int n_t = (lid & 7) * 2 + (sq & 1);
    int m_t = sq >> 1;                      // [0,32)
    int m0 = m_t * 256, n0 = n_t * 256;

    int wv = tid >> 6;                      // 0..7
    int ln = tid & 63;

    int srow = wv * 16 + (ln >> 2);                    // 0..127
    int qsw  = ((ln & 3) - ((srow >> 1) & 3)) & 3;
    const bf16* Ag = PA + (size_t)(m0 + srow) * K + qsw * 8;
    const bf16* Wg = PW + (size_t)(n0 + srow) * K + qsw * 8;
    size_t rowK128 = (size_t)128 * K;

    unsigned short* AsW = As + wv * 512;
    unsigned short* BsW = Bs + wv * 512;

    // wave: m-slot (wv>>2) of 2 x 128 rows; n-slot (wv&3) of 4 x 64 cols
    int wm = (wv >> 2) * 128, wn = (wv & 3) * 64;
    int ra0 = wm + (ln & 15);
    int rb0 = wn + (ln & 15);
    int qa  = ln >> 4;
    int abase = ra0 * 32 + (((qa + ((ra0 >> 1) & 3)) & 3) * 8);
    int bbase = rb0 * 32 + (((qa + ((rb0 >> 1) & 3)) & 3) * 8);

    floatx4 acc[8][4] = {};

    // half-stages: 2 GLDS each. subtile s of K-tile kt into buffer bi.
#define SA0(kt, bi) do { const bf16* _a = Ag + (size_t)(kt) * 64;             \
        unsigned short* _d = AsW + (bi) * 16384;                              \
        GLDS(_a, _d); GLDS(_a + rowK128, _d + 4096); } while (0)
#define SB0(kt, bi) do { const bf16* _b = Wg + (size_t)(kt) * 64;             \
        unsigned short* _d = BsW + (bi) * 16384;                              \
        GLDS(_b, _d); GLDS(_b + rowK128, _d + 4096); } while (0)
#define SA1(kt, bi) do { const bf16* _a = Ag + (size_t)(kt) * 64 + 32;        \
        unsigned short* _d = AsW + (bi) * 16384 + 8192;                       \
        GLDS(_a, _d); GLDS(_a + rowK128, _d + 4096); } while (0)
#define SB1(kt, bi) do { const bf16* _b = Wg + (size_t)(kt) * 64 + 32;        \
        unsigned short* _d = BsW + (bi) * 16384 + 8192;                       \
        GLDS(_b, _d); GLDS(_b + rowK128, _d + 4096); } while (0)

#define MROW(j, bb)                                                           \
    acc[0][j] = __builtin_amdgcn_mfma_f32_16x16x32_bf16(a0, bb, acc[0][j], 0, 0, 0); \
    acc[1][j] = __builtin_amdgcn_mfma_f32_16x16x32_bf16(a1, bb, acc[1][j], 0, 0, 0); \
    acc[2][j] = __builtin_amdgcn_mfma_f32_16x16x32_bf16(a2, bb, acc[2][j], 0, 0, 0); \
    acc[3][j] = __builtin_amdgcn_mfma_f32_16x16x32_bf16(a3, bb, acc[3][j], 0, 0, 0); \
    acc[4][j] = __builtin_amdgcn_mfma_f32_16x16x32_bf16(a4, bb, acc[4][j], 0, 0, 0); \
    acc[5][j] = __builtin_amdgcn_mfma_f32_16x16x32_bf16(a5, bb, acc[5][j], 0, 0, 0); \
    acc[6][j] = __builtin_amdgcn_mfma_f32_16x16x32_bf16(a6, bb, acc[6][j], 0, 0, 0); \
    acc[7][j] = __builtin_amdgcn_mfma_f32_16x16x32_bf16(a7, bb, acc[7][j], 0, 0, 0);

    // phase-pair: odd phase (vmcnt+barrier, A reload, n{0,1}) then even
    // phase (n{2,3}). STGo/STGe = one half-stage each.
#define PPAIR(VMN, bufi, ksub, STGo, STGe)                                    \
    do {                                                                      \
        asm volatile("s_waitcnt vmcnt(" VMN ")" ::: "memory");                \
        __builtin_amdgcn_s_barrier();                                         \
        __builtin_amdgcn_sched_barrier(0);                                    \
        const unsigned short* _A = As + (bufi) * 16384 + (ksub) * 8192 + abase; \
        const unsigned short* _B = Bs + (bufi) * 16384 + (ksub) * 8192 + bbase; \
        bf16x8 a0, a1, a2, a3, a4, a5, a6, a7, b0, b1;                        \
        a0 = *(const bf16x8*)(_A);        a1 = *(const bf16x8*)(_A + 512);    \
        a2 = *(const bf16x8*)(_A + 1024); a3 = *(const bf16x8*)(_A + 1536);   \
        a4 = *(const bf16x8*)(_A + 2048); a5 = *(const bf16x8*)(_A + 2560);   \
        a6 = *(const bf16x8*)(_A + 3072); a7 = *(const bf16x8*)(_A + 3584);   \
        b0 = *(const bf16x8*)(_B);        b1 = *(const bf16x8*)(_B + 512);    \
        STGo;                                                                 \
        asm volatile("s_waitcnt lgkmcnt(0)" ::: "memory");                    \
        __builtin_amdgcn_sched_barrier(0);                                    \
        __builtin_amdgcn_s_setprio(1);                                        \
        MROW(0, b0) MROW(1, b1)                                               \
        __builtin_amdgcn_s_setprio(0);                                        \
        b0 = *(const bf16x8*)(_B + 1024); b1 = *(const bf16x8*)(_B + 1536);   \
        STGe;                                                                 \
        asm volatile("s_waitcnt lgkmcnt(0)" ::: "memory");                    \
        __builtin_amdgcn_sched_barrier(0);                                    \
        __builtin_amdgcn_s_setprio(1);                                        \
        MROW(2, b0) MROW(3, b1)                                               \
        __builtin_amdgcn_s_setprio(0);                                        \
    } while (0)

    int nit = K >> 7;                       // 8 for K=1024 (2 K-tiles/iter)

    // prologue: tile0 complete + tile1 sub0 = 12 GLDS per wave
    SA0(0, 0); SB0(0, 0); SA1(0, 0); SB1(0, 0);
    SA0(1, 1); SB0(1, 1);

    for (int j = 0; j < nit - 1; ++j) {
        int t0 = 2 * j;
        PPAIR("8", 0, 0, SA1(t0 + 1, 1), SB1(t0 + 1, 1));   // ph1-2
        PPAIR("8", 0, 1, SA0(t0 + 2, 0), SB0(t0 + 2, 0));   // ph3-4
        PPAIR("8", 1, 0, SA1(t0 + 2, 0), SB1(t0 + 2, 0));   // ph5-6
        PPAIR("8", 1, 1, SA0(t0 + 3, 1), SB0(t0 + 3, 1));   // ph7-8
    }
    {   // peeled last iteration: only tile (2j+1)'s sub1 still to stage
        int t0 = 2 * (nit - 1);
        PPAIR("8", 0, 0, SA1(t0 + 1, 1), SB1(t0 + 1, 1));
        PPAIR("8", 0, 1, ((void)0), ((void)0));
        PPAIR("4", 1, 0, ((void)0), ((void)0));
        PPAIR("0", 1, 1, ((void)0), ((void)0));
    }

#undef SA0
#undef SB0
#undef SA1
#undef SB1
#undef MROW
#undef PPAIR

    int row0 = (ln >> 4) * 4;
    int colb = n0 + wn + (ln & 15);
#pragma unroll
    for (int i = 0; i < 8; ++i) {
        int gm = m0 + wm + i * 16 + row0;
#pragma unroll
        for (int j = 0; j < 4; ++j) {
            int gn = colb + j * 16;
#pragma unroll
            for (int r = 0; r < 4; ++r) {
                size_t idx = (size_t)(gm + r) * N + gn;
                float v = acc[i][j][r];
                if (epi == EPI_RELU2) { float t2 = fmaxf(v, 0.0f); v = t2 * t2; }
                else if (epi == EPI_SIG) v = 1.0f / (1.0f + __expf(-v));
                if (obf) ((bf16*)PY)[idx] = (bf16)v;
                else     ((float*)PY)[idx] = v;
            }
        }
    }
}

// ---------------------------------------------------------------------------
// WKV segmented scan (3 passes), log-space stabilized state (aa,bb)*e^pp.
// ---------------------------------------------------------------------------
__global__ __launch_bounds__(256) void wkv_seg(const float* __restrict__ k,
                                               const float* __restrict__ v,
                                               const float* __restrict__ decay,
                                               float* __restrict__ sa,
                                               float* __restrict__ sb,
                                               float* __restrict__ sp)
{
    int idx = blockIdx.x * 256 + threadIdx.x;   // (b*NSEG+seg)*C + c
    int c   = idx & (C_DIM - 1);
    int bs  = idx >> 10;
    int seg = bs & (NSEG - 1);
    int b   = bs >> 5;
    float w = -__expf(decay[c]);
    size_t base = ((size_t)b * T_DIM + (size_t)seg * SEGL) * C_DIM + c;
    float aa = 0.f, bb = 0.f, pp = -1e38f;
    for (int t = 0; t < SEGL; ++t) {
        size_t off = base + (size_t)t * C_DIM;
        float kk = k[off], vv = v[off];
        float ww2 = pp + w;
        float p2  = fmaxf(ww2, kk);
        float e1  = __expf(ww2 - p2);
        float e2  = __expf(kk - p2);
        aa = e1 * aa + e2 * vv;
        bb = e1 * bb + e2;
        pp = p2;
    }
    sa[idx] = aa; sb[idx] = bb; sp[idx] = pp;
}

__global__ __launch_bounds__(256) void wkv_comb(const float* __restrict__ sa,
                                                const float* __restrict__ sb,
                                                const float* __restrict__ sp,
                                                const float* __restrict__ decay,
                                                float* __restrict__ ia,
                                                float* __restrict__ ib,
                                                float* __restrict__ ip)
{
    int idx = blockIdx.x * 256 + threadIdx.x;   // b*C + c
    int c = idx & (C_DIM - 1);
    int b = idx >> 10;
    float wL = -__expf(decay[c]) * (float)SEGL;
    float aa = 0.f, bb = 0.f, pp = -1e38f;
    size_t base = (size_t)b * NSEG * C_DIM + c;
    for (int j = 0; j < NSEG; ++j) {
        size_t o = base + (size_t)j * C_DIM;
        ia[o] = aa; ib[o] = bb; ip[o] = pp;     // incoming state for segment j
        float a_s = sa[o], b_s = sb[o], p_s = sp[o];
        float pd = pp + wL;
        float pn = fmaxf(pd, p_s);
        float e1 = __expf(pd - pn);
        float e2 = __expf(p_s - pn);
        aa = e1 * aa + e2 * a_s;
        bb = e1 * bb + e2 * b_s;
        pp = pn;
    }
}

__global__ __launch_bounds__(256) void wkv_out(const float* __restrict__ k,
                                               const float* __restrict__ v,
                                               const bf16* __restrict__ sr,
                                               const float* __restrict__ decay,
                                               const float* __restrict__ first,
                                               const float* __restrict__ ia,
                                               const float* __restrict__ ib,
                                               const float* __restrict__ ip,
                                               bf16* __restrict__ out)
{
    int idx = blockIdx.x * 256 + threadIdx.x;   // (b*NSEG+seg)*C + c
    int c   = idx & (C_DIM - 1);
    int bs  = idx >> 10;
    int seg = bs & (NSEG - 1);
    int b   = bs >> 5;
    float w = -__expf(decay[c]);
    float u = first[c];
    float aa = ia[idx], bb = ib[idx], pp = ip[idx];
    size_t base = ((size_t)b * T_DIM + (size_t)seg * SEGL) * C_DIM + c;
    for (int t = 0; t < SEGL; ++t) {
        size_t off = base + (size_t)t * C_DIM;
        float kk = k[off], vv = v[off];
        float ww = u + kk;
        float p  = fmaxf(pp, ww);
        float e1 = __expf(pp - p);
        float e2 = __expf(ww - p);
        float o  = (e1 * aa + e2 * vv) / (e1 * bb + e2);
        out[off] = (bf16)((float)sr[off] * o);
        float ww2 = pp + w;
        float p2  = fmaxf(ww2, kk);
        float e1b = __expf(ww2 - p2);
        float e2b = __expf(kk - p2);
        aa = e1b * aa + e2b * vv;
        bb = e1b * bb + e2b;
        pp = p2;
    }
}

// ---------------------------------------------------------------------------
// Orchestration: round-10 graph VERBATIM (best measured 528.7us); only
// gemm_w's internals changed. Workspace (byte offsets, 173 MiB peak):
//   [0,26M)    bf16 weights
//   [26,74M)   bf16 acts: xk xv xr -> rwkv | xk2 xr2 sr2
//   [74,170M)  fp32 k (32M), v (32M), sr_b bf16 (16M @138M), kk_b (64M @106M)
//   [170,173M) WKV scan scratch: 6 x 512 KiB
// ---------------------------------------------------------------------------
extern "C" void kernel_launch(void* const* d_in, const int* in_sizes, int n_in,
                              void* d_out, int out_size, void* d_ws, size_t ws_size,
                              hipStream_t stream)
{
    const float* x          = (const float*)d_in[0];
    const float* ln1_w      = (const float*)d_in[1];
    const float* ln1_b      = (const float*)d_in[2];
    const float* ln2_w      = (const float*)d_in[3];
    const float* ln2_b      = (const float*)d_in[4];
    const float* time_decay = (const float*)d_in[5];
    const float* time_first = (const float*)d_in[6];
    const float* tmk        = (const float*)d_in[7];
    const float* tmv        = (const float*)d_in[8];
    const float* tmr        = (const float*)d_in[9];
    const float* att_kw     = (const float*)d_in[10];
    const float* att_vw     = (const float*)d_in[11];
    const float* att_rw     = (const float*)d_in[12];
    const float* att_ow     = (const float*)d_in[13];
    const float* f_tmk      = (const float*)d_in[14];
    const float* f_tmr      = (const float*)d_in[15];
    const float* f_kw       = (const float*)d_in[16];
    const float* f_rw       = (const float*)d_in[17];
    const float* f_vw       = (const float*)d_in[18];
    float* out = (float*)d_out;

    char* W8 = (char*)d_ws;
    bf16* kw_b  = (bf16*)(W8 + 0 * MB);
    bf16* vw_b  = (bf16*)(W8 + 2 * MB);
    bf16* rw_b  = (bf16*)(W8 + 4 * MB);
    bf16* ow_b  = (bf16*)(W8 + 6 * MB);
    bf16* fkw_b = (bf16*)(W8 + 8 * MB);
    bf16* frw_b = (bf16*)(W8 + 16 * MB);
    bf16* fvw_b = (bf16*)(W8 + 18 * MB);

    bf16*  xk_b   = (bf16*)(W8 + 26 * MB);
    bf16*  xv_b   = (bf16*)(W8 + 42 * MB);
    bf16*  xr_b   = (bf16*)(W8 + 58 * MB);
    bf16*  rwkv_b = xk_b;
    bf16*  xk2_b  = (bf16*)(W8 + 26 * MB);
    bf16*  xr2_b  = (bf16*)(W8 + 42 * MB);
    bf16*  sr2_b  = (bf16*)(W8 + 58 * MB);
    float* kbuf   = (float*)(W8 + 74 * MB);
    float* vbuf   = (float*)(W8 + 106 * MB);
    bf16*  srb_b  = (bf16*)(W8 + 138 * MB);     // 16 MiB
    bf16*  kk_b   = (bf16*)(W8 + 106 * MB);     // 64 MiB, overlaps vbuf; kk is
    // written only AFTER wkv_out has consumed kbuf/vbuf (ChannelMix phase).

    size_t KB512 = (size_t)512 * 1024;
    float* sc_a = (float*)(W8 + 170 * MB);
    float* sc_b = (float*)(W8 + 170 * MB + 1 * KB512);
    float* sc_p = (float*)(W8 + 170 * MB + 2 * KB512);
    float* in_a = (float*)(W8 + 170 * MB + 3 * KB512);
    float* in_b = (float*)(W8 + 170 * MB + 4 * KB512);
    float* in_p = (float*)(W8 + 170 * MB + 5 * KB512);

    // single-dispatch weight conversion
    int nC4 = C_DIM * C_DIM / 4, nF4 = FFN_DIM * C_DIM / 4;
    W7 w7;
    const float* srcs[7] = { att_kw, att_vw, att_rw, att_ow, f_kw, f_rw, f_vw };
    bf16*        dsts[7] = { kw_b, vw_b, rw_b, ow_b, fkw_b, frw_b, fvw_b };
    int          cnts[7] = { nC4, nC4, nC4, nC4, nF4, nC4, nF4 };
    int cum = 0;
    for (int i = 0; i < 7; ++i) { w7.s[i] = srcs[i]; w7.d[i] = dsts[i]; w7.cum[i] = cum; cum += cnts[i]; }
    w7.cum[7] = cum;                                   // 3407872, /256 = 13312
    f2b7_kernel<<<cum / 256, 256, 0, stream>>>(w7);

    int segGrid = B_DIM * NSEG * C_DIM / 256;   // 512

    auto launch = [&](const bf16* A, const bf16* W, void* Y, const float* X2,
                      const bf16* S, int N, int K, int epi, int obf) {
        GemmArgs p; p.A = A; p.W = W; p.Y = Y; p.X2 = X2; p.S = S;
        p.N = N; p.K = K; p.epi = epi; p.outBf16 = obf;
        int grid = (NROWS / 256) * (N / 128);
        gemm_p<<<grid, 512, 0, stream>>>(p);
    };

    // --- TimeMix ---
    lnmix_kernel<true><<<NROWS, 256, 0, stream>>>(x, ln1_w, ln1_b, tmk, tmv, tmr,
                                                  xk_b, xv_b, xr_b);
    launch(xk_b, kw_b, kbuf,  nullptr, nullptr, C_DIM, C_DIM, EPI_NONE, 0);
    launch(xv_b, vw_b, vbuf,  nullptr, nullptr, C_DIM, C_DIM, EPI_NONE, 0);
    launch(xr_b, rw_b, srb_b, nullptr, nullptr, C_DIM, C_DIM, EPI_SIG,  1);
    wkv_seg<<<segGrid, 256, 0, stream>>>(kbuf, vbuf, time_decay, sc_a, sc_b, sc_p);
    wkv_comb<<<B_DIM * C_DIM / 256, 256, 0, stream>>>(sc_a, sc_b, sc_p, time_decay, in_a, in_b, in_p);
    wkv_out<<<segGrid, 256, 0, stream>>>(kbuf, vbuf, srb_b, time_decay, time_first,
                                         in_a, in_b, in_p, rwkv_b);
    launch(rwkv_b, ow_b, out, x, nullptr, C_DIM, C_DIM, EPI_ADD, 0);

    // --- ChannelMix ---
    lnmix_kernel<false><<<NROWS, 256, 0, stream>>>(out, ln2_w, ln2_b, f_tmk, nullptr, f_tmr,
                                                   xk2_b, nullptr, xr2_b);
    launch(xr2_b, frw_b, sr2_b, nullptr, nullptr, C_DIM,   C_DIM, EPI_SIG,   1);
    {   // FFN-up on the 8-phase 256x256 kernel: 32 x 16 = 512 blocks
        GemmArgs p; p.A = xk2_b; p.W = fkw_b; p.Y = kk_b; p.X2 = nullptr; p.S = nullptr;
        p.N = FFN_DIM; p.K = C_DIM; p.epi = EPI_RELU2; p.outBf16 = 1;
        gemm_w<<<(NROWS / 256) * (FFN_DIM / 256), 512, 0, stream>>>(p);
    }
    launch(kk_b,  fvw_b, out,   out,     sr2_b,   C_DIM, FFN_DIM, EPI_SCALEADD, 0);
}